// Round 8
// baseline (175.286 us; speedup 1.0000x reference)
//
#include <hip/hip_runtime.h>

#define BS 8
#define SEQ 512
#define CDIM 512
#define NC 5
#define IMG_H 768
#define IMG_W 768
#define HW (IMG_H * IMG_W)
#define NTOK (BS * SEQ)
#define NBLK (NTOK / 4)     // 1024 blocks = 4/CU, all co-resident, one round

// ws layout (byte offsets). NO fill/memset nodes (R5 lesson: extra nodes /
// passes always lost). Ticket counter needs no init: atomicInc with
// val=NBLK-1 wraps ANY start >= NBLK-1 (0xAA poison or leftover 1023) to 0
// on the first increment; the 1024th increment uniquely returns NBLK-2.
#define WS_CNT_OFF   0
#define WS_PART_OFF  4096

// R8 = R4's gather (exec-mask-predicated loads -- measured best; address-
// clamped unconditional loads in R7 inflated the line footprint ~2.5x and
// cost +28 us) + single-dispatch fusion via the validated ticket scheme.
__global__ __launch_bounds__(256) void fused_kernel(
    const float* __restrict__ emb,     // [BS, SEQ, CDIM]
    const float* __restrict__ cls,     // [BS, NC, H, W]
    const float* __restrict__ Wc,      // [NC, CDIM]
    const float* __restrict__ bc,      // [NC]
    const int*   __restrict__ coords,  // [BS, SEQ, 4] (x0,y0,x1,y1)
    const int*   __restrict__ mask,    // [BS, SEQ]
    float2* __restrict__ partials,     // [NBLK]
    unsigned int* __restrict__ counter,
    float* __restrict__ out)
{
    const int t     = threadIdx.x;
    const int wave  = t >> 6;
    const int lane  = t & 63;
    const int token = blockIdx.x * 4 + wave;
    const int b     = token >> 9;      // token / SEQ

    int x0 = coords[token * 4 + 0];
    int y0 = coords[token * 4 + 1];
    int x1 = coords[token * 4 + 2];
    int y1 = coords[token * 4 + 3];
    if (y1 == y0) y1++;                // degenerate-box fix (ref semantics)
    if (x1 == x0) x1++;
    if (x1 > IMG_W) x1 = IMG_W;
    if (y1 > IMG_H) y1 = IMG_H;

    // ---- box histogram: x = x0+lane, exec-masked; independent row loads ----
    // packed u64 hist: class c in bits [12c,12c+12); max area 945 < 4095
    unsigned long long hp = 0ull;
    {
        const int xx = x0 + lane;
        const bool xok = (xx < x1);    // width <= 63 -> single column step
        const float* p0 = cls + (size_t)b * NC * HW + y0 * IMG_W + xx;
#pragma unroll 4
        for (int yy = y0; yy < y1; ++yy, p0 += IMG_W) {
            if (xok) {                 // exec-mask: masked lanes issue NO vmem
                const float v0 = p0[0 * HW];
                const float v1 = p0[1 * HW];
                const float v2 = p0[2 * HW];
                const float v3 = p0[3 * HW];
                const float v4 = p0[4 * HW];
                int lab = 0; float best = v0;    // strict > == first-max
                if (v1 > best) { best = v1; lab = 1; }
                if (v2 > best) { best = v2; lab = 2; }
                if (v3 > best) { best = v3; lab = 3; }
                if (v4 > best) { best = v4; lab = 4; }
                hp += 1ull << (lab * 12);
            }
        }
    }

    // ---- logits partials: 8 emb elems / lane vs 5 rows (Wc L1-hot) ----
    const float* e = emb + (size_t)token * CDIM + lane * 8;
    const float4 e0 = *(const float4*)(e);
    const float4 e1 = *(const float4*)(e + 4);
    float part[NC];
#pragma unroll
    for (int c = 0; c < NC; ++c) {
        const float* w = Wc + c * CDIM + lane * 8;
        const float4 w0 = *(const float4*)(w);
        const float4 w1 = *(const float4*)(w + 4);
        part[c] = e0.x * w0.x + e0.y * w0.y + e0.z * w0.z + e0.w * w0.w
                + e1.x * w1.x + e1.y * w1.y + e1.z * w1.z + e1.w * w1.w;
    }

    // ---- wave reduce (5 floats + 1 u64) ----
#pragma unroll
    for (int off = 32; off >= 1; off >>= 1) {
#pragma unroll
        for (int c = 0; c < NC; ++c) part[c] += __shfl_down(part[c], off);
        hp += __shfl_down(hp, off);
    }

    __shared__ float2 s_pair[4];
    __shared__ int s_last;
    if (lane == 0) {
        float l[NC];
#pragma unroll
        for (int c = 0; c < NC; ++c) l[c] = part[c] + bc[c];

        int maj = 0;
        int bestc = (int)(hp & 4095);
#pragma unroll
        for (int c = 1; c < NC; ++c) {
            const int hc = (int)((hp >> (12 * c)) & 4095);
            if (hc > bestc) { bestc = hc; maj = c; }   // first-max tiebreak
        }
        float m = l[0];
#pragma unroll
        for (int c = 1; c < NC; ++c) m = fmaxf(m, l[c]);
        float s = 0.0f;
#pragma unroll
        for (int c = 0; c < NC; ++c) s += __expf(l[c] - m);
        const float nll = m + __logf(s) - l[maj];
        const float mk = (mask[token] == 1) ? 1.0f : 0.0f;
        s_pair[wave] = make_float2(nll * mk, mk);
    }
    __syncthreads();

    if (t == 0) {
        const float2 a = s_pair[0], b2 = s_pair[1],
                     c2 = s_pair[2], d2 = s_pair[3];
        partials[blockIdx.x] = make_float2(a.x + b2.x + c2.x + d2.x,
                                           a.y + b2.y + c2.y + d2.y);
        __threadfence();   // release partials device-wide before ticket
        const unsigned int old = atomicInc(counter, NBLK - 1u);
        s_last = (old == NBLK - 2u);   // unique winner on the 1024th ticket
    }
    __syncthreads();

    if (s_last) {                      // winner block reduces 1024 partials
        __threadfence();               // acquire: all partials visible
        float a = 0.0f, bsum = 0.0f;
#pragma unroll
        for (int i = t; i < NBLK; i += 256) {
            const float2 v = partials[i];
            a += v.x; bsum += v.y;
        }
#pragma unroll
        for (int off = 32; off >= 1; off >>= 1) {
            a    += __shfl_down(a, off);
            bsum += __shfl_down(bsum, off);
        }
        __shared__ float sa[4], sb[4];
        if (lane == 0) { sa[wave] = a; sb[wave] = bsum; }
        __syncthreads();
        if (t == 0) {
            a    = sa[0] + sa[1] + sa[2] + sa[3];
            bsum = sb[0] + sb[1] + sb[2] + sb[3];
            out[0] = a / bsum;
        }
    }
}

extern "C" void kernel_launch(void* const* d_in, const int* in_sizes, int n_in,
                              void* d_out, int out_size, void* d_ws, size_t ws_size,
                              hipStream_t stream) {
    const float* emb    = (const float*)d_in[0];  // [8,512,512] f32
    const float* cls    = (const float*)d_in[1];  // [8,5,768,768] f32
    const float* Wc     = (const float*)d_in[2];  // [5,512] f32
    const float* bc     = (const float*)d_in[3];  // [5] f32
    const int*   coords = (const int*)d_in[4];    // [8,512,4] i32
    const int*   mask   = (const int*)d_in[5];    // [8,512] i32
    float* out = (float*)d_out;

    char* ws = (char*)d_ws;
    unsigned int* counter  = (unsigned int*)(ws + WS_CNT_OFF);
    float2*       partials = (float2*)(ws + WS_PART_OFF);

    fused_kernel<<<NBLK, 256, 0, stream>>>(emb, cls, Wc, bc, coords, mask,
                                           partials, counter, out);
}

// Round 9
// 146.283 us; speedup vs baseline: 1.1983x; 1.1983x over previous
//
#include <hip/hip_runtime.h>

#define BS 8
#define SEQ 512
#define CDIM 512
#define NC 5
#define IMG_H 768
#define IMG_W 768
#define HW (IMG_H * IMG_W)
#define NTOK (BS * SEQ)
#define NBLK (NTOK / 4)   // 1024 blocks = 4/CU, all co-resident, one round

// R9 = R4 (best measured: 147.3 us) + XCD-affinity swizzle.
// R8 proved single-kernel ticket fusion costs ~+28 us (1024 device-scope
// __threadfence L2-writebacks on poison-dirty L2s + winner-block tail), so
// we keep the two-dispatch structure: token kernel -> 1024 float2 partials,
// tiny finalize kernel.
// Swizzle: blocks dispatch round-robin over 8 XCDs; batch = blockIdx & 7
// pins each image's boxes to one XCD so its touched lines (~3 MB/image)
// fit that XCD's 4 MB L2 and box-overlap re-touches hit L2 instead of HBM.
// If dispatch order differs this is a pure relabeling (still correct).
__global__ __launch_bounds__(256) void token_kernel(
    const float* __restrict__ emb,     // [BS, SEQ, CDIM]
    const float* __restrict__ cls,     // [BS, NC, H, W]
    const float* __restrict__ Wc,      // [NC, CDIM]
    const float* __restrict__ bc,      // [NC]
    const int*   __restrict__ coords,  // [BS, SEQ, 4] (x0,y0,x1,y1)
    const int*   __restrict__ mask,    // [BS, SEQ]
    float2* __restrict__ ws)           // [NBLK] block partial (nll*m, m)
{
    const int t     = threadIdx.x;
    const int wave  = t >> 6;
    const int lane  = t & 63;
    // XCD-affinity: batch = blockIdx & 7, slot within batch = blockIdx >> 3
    const int b     = blockIdx.x & 7;
    const int slot  = blockIdx.x >> 3;            // 0..127
    const int token = (b << 9) + slot * 4 + wave; // batch-local 4-token group

    int x0 = coords[token * 4 + 0];
    int y0 = coords[token * 4 + 1];
    int x1 = coords[token * 4 + 2];
    int y1 = coords[token * 4 + 3];
    if (y1 == y0) y1++;            // degenerate-box fix (reference semantics)
    if (x1 == x0) x1++;
    if (x1 > IMG_W) x1 = IMG_W;
    if (y1 > IMG_H) y1 = IMG_H;

    // ---- box histogram: x = x0+lane, exec-masked loads (measured best:
    // masked-off lanes issue NO vmem; address-clamping inflated footprint
    // 2.5x in R7). Rows independent, unroll 4. ----
    unsigned long long hp = 0ull;  // packed hist: class c in bits [12c,12c+12)
    {
        const int xx = x0 + lane;
        const bool xok = (xx < x1);            // width <= 63 -> one col step
        const float* p0 = cls + (size_t)b * NC * HW + y0 * IMG_W + xx;
#pragma unroll 4
        for (int yy = y0; yy < y1; ++yy, p0 += IMG_W) {
            if (xok) {
                const float v0 = p0[0 * HW];
                const float v1 = p0[1 * HW];
                const float v2 = p0[2 * HW];
                const float v3 = p0[3 * HW];
                const float v4 = p0[4 * HW];
                int lab = 0; float best = v0;  // strict > == first-max
                if (v1 > best) { best = v1; lab = 1; }
                if (v2 > best) { best = v2; lab = 2; }
                if (v3 > best) { best = v3; lab = 3; }
                if (v4 > best) { best = v4; lab = 4; }
                hp += 1ull << (lab * 12);
            }
        }
    }

    // ---- logits partials: 8 emb elems / lane vs 5 rows (Wc L1-hot) ----
    const float* e = emb + (size_t)token * CDIM + lane * 8;
    const float4 e0 = *(const float4*)(e);
    const float4 e1 = *(const float4*)(e + 4);
    float part[NC];
#pragma unroll
    for (int c = 0; c < NC; ++c) {
        const float* w = Wc + c * CDIM + lane * 8;
        const float4 w0 = *(const float4*)(w);
        const float4 w1 = *(const float4*)(w + 4);
        part[c] = e0.x * w0.x + e0.y * w0.y + e0.z * w0.z + e0.w * w0.w
                + e1.x * w1.x + e1.y * w1.y + e1.z * w1.z + e1.w * w1.w;
    }

    // ---- wave reduce (5 floats + 1 ull) ----
#pragma unroll
    for (int off = 32; off >= 1; off >>= 1) {
#pragma unroll
        for (int c = 0; c < NC; ++c) part[c] += __shfl_down(part[c], off);
        hp += __shfl_down(hp, off);
    }

    __shared__ float2 s_pair[4];
    if (lane == 0) {
        float l[NC];
#pragma unroll
        for (int c = 0; c < NC; ++c) l[c] = part[c] + bc[c];

        int maj = 0;
        int bestc = (int)(hp & 4095);
#pragma unroll
        for (int c = 1; c < NC; ++c) {
            const int hc = (int)((hp >> (12 * c)) & 4095);
            if (hc > bestc) { bestc = hc; maj = c; }   // first-max tiebreak
        }

        float m = l[0];
#pragma unroll
        for (int c = 1; c < NC; ++c) m = fmaxf(m, l[c]);
        float s = 0.0f;
#pragma unroll
        for (int c = 0; c < NC; ++c) s += __expf(l[c] - m);
        const float nll = m + __logf(s) - l[maj];

        const float mk = (mask[token] == 1) ? 1.0f : 0.0f;
        s_pair[wave] = make_float2(nll * mk, mk);
    }
    __syncthreads();

    if (t == 0) {
        const float2 a = s_pair[0], b2 = s_pair[1],
                     c2 = s_pair[2], d2 = s_pair[3];
        ws[blockIdx.x] = make_float2(a.x + b2.x + c2.x + d2.x,
                                     a.y + b2.y + c2.y + d2.y);
    }
}

__global__ __launch_bounds__(256) void finalize_kernel(
    const float2* __restrict__ ws, float* __restrict__ out)
{
    float a = 0.0f, bsum = 0.0f;
#pragma unroll
    for (int i = threadIdx.x; i < NBLK; i += 256) {
        const float2 v = ws[i];
        a += v.x; bsum += v.y;
    }
#pragma unroll
    for (int off = 32; off >= 1; off >>= 1) {
        a    += __shfl_down(a, off);
        bsum += __shfl_down(bsum, off);
    }
    __shared__ float sa[4], sb[4];
    const int wave = threadIdx.x >> 6;
    if ((threadIdx.x & 63) == 0) { sa[wave] = a; sb[wave] = bsum; }
    __syncthreads();
    if (threadIdx.x == 0) {
        a    = sa[0] + sa[1] + sa[2] + sa[3];
        bsum = sb[0] + sb[1] + sb[2] + sb[3];
        out[0] = a / bsum;
    }
}

extern "C" void kernel_launch(void* const* d_in, const int* in_sizes, int n_in,
                              void* d_out, int out_size, void* d_ws, size_t ws_size,
                              hipStream_t stream) {
    const float* emb    = (const float*)d_in[0];  // [8,512,512] f32
    const float* cls    = (const float*)d_in[1];  // [8,5,768,768] f32
    const float* Wc     = (const float*)d_in[2];  // [5,512] f32
    const float* bc     = (const float*)d_in[3];  // [5] f32
    const int*   coords = (const int*)d_in[4];    // [8,512,4] i32
    const int*   mask   = (const int*)d_in[5];    // [8,512] i32
    float* out = (float*)d_out;
    float2* ws = (float2*)d_ws;                   // NBLK float2 partials

    token_kernel<<<NBLK, 256, 0, stream>>>(emb, cls, Wc, bc, coords, mask, ws);
    finalize_kernel<<<1, 256, 0, stream>>>(ws, out);
}